// Round 18
// baseline (88.033 us; speedup 1.0000x reference)
//
#include <hip/hip_runtime.h>

#define NPROTO 2048
#define NOUT   200
#define LAT    40
#define NWP    200     // wsum producer blocks
#define NPP    32      // proto-stat producer blocks
#define NPROD  232     // producers = 8 buckets x 29
#define FBLK   2048    // grid
#define RPB    16      // rows per block
#define NB1    64

// Device-global sync state: zero-init at load; islast resets each call.
// One counter/flag per 128B line (r6: same-line LLC RMWs ~10ns serialized;
// r9: 2048 pollers on ONE flag line = the 80us failure -> 64 replicas).
__device__ int g_pc1[8 * 32];    // producer arrival L1
__device__ int g_pc2[32];        // producer arrival L2
__device__ int g_flag[NB1 * 32]; // stage-1 ready flag, 64 replicas
__device__ int g_ac1[64 * 32];   // finish arrival L1
__device__ int g_ac2[32];        // finish arrival L2

// ws float layout:
//  [0..199]        wsum[200]
//  [200..231]      proto_sq partials (32)
//  [256..1535]     proto_sum partials [32][40]
//  ull[1024..3071] packed {min,sum} per block (floats 2048..6143)

__device__ __forceinline__ unsigned long long pack2f(float a, float b) {
    union { float f[2]; unsigned long long u; } c;
    c.f[0] = a; c.f[1] = b; return c.u;
}

__device__ __forceinline__ void producer_arrive(int blk) {
    const int c = blk & 7;
    int p1 = __hip_atomic_fetch_add(&g_pc1[c * 32], 1, __ATOMIC_ACQ_REL,
                                    __HIP_MEMORY_SCOPE_AGENT);
    if (p1 == NPROD / 8 - 1) {
        int p2 = __hip_atomic_fetch_add(&g_pc2[0], 1, __ATOMIC_ACQ_REL,
                                        __HIP_MEMORY_SCOPE_AGENT);
        if (p2 == 7) {
            #pragma unroll
            for (int f = 0; f < NB1; ++f)
                __hip_atomic_store(&g_flag[f * 32], 1, __ATOMIC_RELEASE,
                                   __HIP_MEMORY_SCOPE_AGENT);
        }
    }
}

__global__ __launch_bounds__(256, 4) void pc_one(
    const float* __restrict__ x, const float* __restrict__ protos,
    const float* __restrict__ w, const float* __restrict__ bias,
    float* __restrict__ ws, float* __restrict__ out)
{
    __shared__ float4 sx[RPB * 10];   // this block's 16 x-rows (2.5KB)
    __shared__ float  sdim[6][40];
    __shared__ float  ssq4[4];
    __shared__ float  sred[4];
    __shared__ float  sps[40];
    __shared__ float  spsq;
    __shared__ float2 swb[100];
    __shared__ float2 sbb[100];
    __shared__ float  sd[RPB];
    __shared__ int    islast;
    __shared__ float  fmn[4], fsm[4];

    const int t   = threadIdx.x;
    const int blk = blockIdx.x;

    // 0) x prefetch (coalesced) — overlaps the producer phase
    if (t < RPB * 10)
        sx[t] = ((const float4*)(x + blk * (RPB * LAT)))[t];

    // 1) stage-1 producers (blocks 0..231); data published via agent-scope
    //    atomic stores (write-through, no dirty-L2), ACQ_REL arrival chain.
    if (blk < NWP) {
        float acc = 0.f;
        const float* row = w + blk * NPROTO;
        #pragma unroll
        for (int k = 0; k < 8; ++k) acc += row[k * 256 + t];
        #pragma unroll
        for (int off = 32; off > 0; off >>= 1) acc += __shfl_down(acc, off, 64);
        if ((t & 63) == 0) sred[t >> 6] = acc;
        __syncthreads();
        if (t == 0) {
            __hip_atomic_store(&ws[blk], sred[0] + sred[1] + sred[2] + sred[3],
                               __ATOMIC_RELAXED, __HIP_MEMORY_SCOPE_AGENT);
            producer_arrive(blk);   // wave-level vmcnt covers the store
        }
    } else if (blk < NPROD) {
        const int rel = blk - NWP;
        float sum = 0.f, sq = 0.f;
        if (t < 240) {
            const int d = t % 40, g = t / 40;  // invariant: strides % 40 == 0
            for (int idx = rel * 240 + t; idx < NPROTO * LAT; idx += NPP * 240) {
                float v = protos[idx];
                sum += v; sq += v * v;
            }
            sdim[g][d] = sum;
        }
        #pragma unroll
        for (int off = 32; off > 0; off >>= 1) sq += __shfl_down(sq, off, 64);
        if ((t & 63) == 0) ssq4[t >> 6] = sq;
        __syncthreads();
        if (t < 40) {                          // wave 0 publishes partials
            float s = 0.f;
            #pragma unroll
            for (int g2 = 0; g2 < 6; ++g2) s += sdim[g2][t];
            __hip_atomic_store(&ws[256 + rel * 40 + t], s,
                               __ATOMIC_RELAXED, __HIP_MEMORY_SCOPE_AGENT);
        }
        if (t == 0) {
            __hip_atomic_store(&ws[200 + rel], ssq4[0] + ssq4[1] + ssq4[2] + ssq4[3],
                               __ATOMIC_RELAXED, __HIP_MEMORY_SCOPE_AGENT);
            producer_arrive(blk);   // vmcnt is wave-level: covers t<40 stores
        }
    }

    // 2) wait on THIS block's flag replica, then one acquire fence
    if (t == 0) {
        while (__hip_atomic_load(&g_flag[(blk & (NB1 - 1)) * 32],
                                 __ATOMIC_RELAXED, __HIP_MEMORY_SCOPE_AGENT) == 0)
            __builtin_amdgcn_s_sleep(8);
    }
    __syncthreads();
    __builtin_amdgcn_fence(__ATOMIC_ACQUIRE, "agent");

    // 3) consumer prologue: PLAIN cached loads (r9's atomic-load storm was
    //    the 2nd half of its 80us; after the acquire fence these hit L2)
    if (t < 40) {
        float s = 0.f;
        #pragma unroll
        for (int j = 0; j < NPP; ++j) s += ws[256 + j * 40 + t];
        sps[t] = s;
    } else if (t == 40) {
        float s = 0.f;
        #pragma unroll
        for (int j = 0; j < NPP; ++j) s += ws[200 + j];
        spsq = s;
    }
    if (t >= 56 && t < 156) swb[t - 56]  = ((const float2*)ws)[t - 56];
    if (t >= 156)           sbb[t - 156] = ((const float2*)bias)[t - 156];
    __syncthreads();

    // 4) d for this block's 16 rows
    float pmn = 0.f, psm = 0.f;
    if (t < RPB) {
        float ssq2 = 0.f, dot = 0.f;
        #pragma unroll
        for (int k = 0; k < 10; ++k) {
            float4 v = sx[t * 10 + k];
            ssq2 += v.x * v.x + v.y * v.y + v.z * v.z + v.w * v.w;
            dot  += v.x * sps[4 * k] + v.y * sps[4 * k + 1] +
                    v.z * sps[4 * k + 2] + v.w * sps[4 * k + 3];
        }
        const float d = sqrtf(2048.f * ssq2 - 2.f * dot + spsq);
        sd[t] = d;
        float mn = d, sm = d;
        #pragma unroll
        for (int off = 8; off > 0; off >>= 1) {
            mn = fminf(mn, __shfl_down(mn, off, 64));
            sm += __shfl_down(sm, off, 64);
        }
        pmn = mn; psm = sm;
    }
    __syncthreads();

    // 5) write 16x200 slab, 8B system-scope stores (r15-proven best path)
    unsigned long long* o = (unsigned long long*)(out + 2);
    const int base = blk * (RPB * 100);
    for (int idx = t; idx < RPB * 100; idx += 256) {
        const int i = idx / 100;
        const int j = idx - i * 100;
        const float  dd = sd[i];
        const float2 wv = swb[j];
        const float2 bv = sbb[j];
        __hip_atomic_store(o + base + idx,
                           pack2f(dd * wv.x + bv.x, dd * wv.y + bv.y),
                           __ATOMIC_RELAXED, __HIP_MEMORY_SCOPE_SYSTEM);
    }

    // 6) hierarchical finish arrival (r7-proven)
    unsigned long long* pptr = (unsigned long long*)ws + 1024;
    if (t == 0) {
        __hip_atomic_store(pptr + blk, pack2f(pmn, psm),
                           __ATOMIC_RELAXED, __HIP_MEMORY_SCOPE_AGENT);
        asm volatile("s_waitcnt vmcnt(0)" ::: "memory");
        const int c = blk & 63;
        int last = 0;
        int p1 = __hip_atomic_fetch_add(&g_ac1[c * 32], 1, __ATOMIC_RELAXED,
                                        __HIP_MEMORY_SCOPE_AGENT);
        if (p1 == FBLK / 64 - 1) {
            int p2 = __hip_atomic_fetch_add(&g_ac2[0], 1, __ATOMIC_RELAXED,
                                            __HIP_MEMORY_SCOPE_AGENT);
            last = (p2 == 63);
        }
        islast = last;
    }
    __syncthreads();

    // 7) last block: final reduce + reset ALL sync state for next replay
    if (islast) {
        __builtin_amdgcn_fence(__ATOMIC_ACQUIRE, "agent");
        float mn = 3.4e38f, sm = 0.f;
        #pragma unroll
        for (int j = 0; j < FBLK / 256; ++j) {
            unsigned long long v = __hip_atomic_load(pptr + j * 256 + t,
                                                     __ATOMIC_RELAXED,
                                                     __HIP_MEMORY_SCOPE_AGENT);
            union { unsigned long long u; float f[2]; } c2; c2.u = v;
            mn = fminf(mn, c2.f[0]);
            sm += c2.f[1];
        }
        #pragma unroll
        for (int off = 32; off > 0; off >>= 1) {
            mn = fminf(mn, __shfl_down(mn, off, 64));
            sm += __shfl_down(sm, off, 64);
        }
        if ((t & 63) == 0) { fmn[t >> 6] = mn; fsm[t >> 6] = sm; }
        __syncthreads();
        if (t == 0) {
            out[0] = fminf(fminf(fmn[0], fmn[1]), fminf(fmn[2], fmn[3]));
            out[1] = (fsm[0] + fsm[1] + fsm[2] + fsm[3]) * (1.0f / 32768.0f);
        }
        if (t < 64) {
            __hip_atomic_store(&g_ac1[t * 32], 0, __ATOMIC_RELAXED, __HIP_MEMORY_SCOPE_AGENT);
            __hip_atomic_store(&g_flag[t * 32], 0, __ATOMIC_RELAXED, __HIP_MEMORY_SCOPE_AGENT);
        }
        if (t < 8)
            __hip_atomic_store(&g_pc1[t * 32], 0, __ATOMIC_RELAXED, __HIP_MEMORY_SCOPE_AGENT);
        if (t == 0) {
            __hip_atomic_store(&g_pc2[0], 0, __ATOMIC_RELAXED, __HIP_MEMORY_SCOPE_AGENT);
            __hip_atomic_store(&g_ac2[0], 0, __ATOMIC_RELAXED, __HIP_MEMORY_SCOPE_AGENT);
        }
    }
}

extern "C" void kernel_launch(void* const* d_in, const int* in_sizes, int n_in,
                              void* d_out, int out_size, void* d_ws, size_t ws_size,
                              hipStream_t stream) {
    const float* x      = (const float*)d_in[0];
    const float* protos = (const float*)d_in[1];
    const float* w      = (const float*)d_in[2];
    const float* bias   = (const float*)d_in[3];
    float* out = (float*)d_out;
    float* ws  = (float*)d_ws;

    pc_one<<<FBLK, 256, 0, stream>>>(x, protos, w, bias, ws, out);
}

// Round 19
// 18.323 us; speedup vs baseline: 4.8046x; 4.8046x over previous
//
#include <hip/hip_runtime.h>

#define NPROTO 2048
#define NOUT   200
#define LAT    40
#define PBLK   16      // proto-reduction blocks in stage1
#define FBLK   1024    // fused dist+out blocks
#define RPB    32      // rows per fused block
#define NB1    64      // level-1 arrival buckets (one cache line each)

// ws layout:
//  floats [0..199]      wsum[200]
//  floats [200..215]    proto_sq partials (16)
//  floats [256..895]    proto_sum partials [16][40]
//  ull    [1024..2047]  packed {min,sum} partials per block
//  ints   [6400 + c*32] level-1 arrival counters, c=0..63 (128B apart)
//  int    [8448]        level-2 arrival counter

__global__ __launch_bounds__(320) void pc_stage1(const float* __restrict__ protos,
                                                 const float* __restrict__ w,
                                                 float* __restrict__ ws) {
    const int b = blockIdx.x;
    const int t = threadIdx.x;
    __shared__ float sred[5];
    __shared__ float sdim[8][40];
    __shared__ float ssq[5];
    if (b == 0) {                                  // reset arrival counters
        if (t < NB1) ((int*)ws)[6400 + t * 32] = 0;
        if (t == NB1) ((int*)ws)[8448] = 0;
    }
    if (b < NOUT) {
        // wsum[b] = sum_p w[b, p] — float4 loads, 512 vectors
        float acc = 0.f;
        const float4* row = (const float4*)(w + b * NPROTO);
        float4 v0 = row[t];
        acc += v0.x + v0.y + v0.z + v0.w;
        if (t < 192) {
            float4 v1 = row[t + 320];
            acc += v1.x + v1.y + v1.z + v1.w;
        }
        #pragma unroll
        for (int off = 32; off > 0; off >>= 1) acc += __shfl_down(acc, off, 64);
        if ((t & 63) == 0) sred[t >> 6] = acc;
        __syncthreads();
        if (t == 0) ws[b] = sred[0] + sred[1] + sred[2] + sred[3] + sred[4];
    } else {
        // proto partial reduction: 16 blocks x 320 threads, d = t%40 invariant
        const int rel = b - NOUT;          // 0..15
        const int d = t % 40, g = t / 40;  // 8 groups of 40
        float sum = 0.f, sq = 0.f;
        for (int idx = rel * 320 + t; idx < NPROTO * LAT; idx += PBLK * 320) {
            float v = protos[idx];          // coalesced; idx%40 == d always
            sum += v;
            sq  += v * v;
        }
        sdim[g][d] = sum;
        #pragma unroll
        for (int off = 32; off > 0; off >>= 1) sq += __shfl_down(sq, off, 64);
        if ((t & 63) == 0) ssq[t >> 6] = sq;
        __syncthreads();
        if (t < 40) {
            float s = 0.f;
            #pragma unroll
            for (int g2 = 0; g2 < 8; ++g2) s += sdim[g2][t];
            ws[256 + rel * 40 + t] = s;
        }
        if (t == 0) ws[200 + rel] = ssq[0] + ssq[1] + ssq[2] + ssq[3] + ssq[4];
    }
}

__device__ __forceinline__ unsigned long long pack2f(float a, float b) {
    union { float f[2]; unsigned long long u; } c;
    c.f[0] = a; c.f[1] = b; return c.u;
}

__global__ __launch_bounds__(256) void pc_distout(const float* __restrict__ x,
                                                  const float* __restrict__ bias,
                                                  float* __restrict__ ws,
                                                  float* __restrict__ out) {
    __shared__ float4 sx[RPB * 10];   // this block's 32 x-rows (5KB)
    __shared__ float  sps[40];
    __shared__ float  spsq;
    __shared__ float  swx[100], swy[100];  // wsum pairs, split -> bank-conflict-free
    __shared__ float  sbx[100], sby[100];  // bias pairs, split
    __shared__ float  sd[RPB];
    __shared__ int    islast;
    __shared__ float  fmn[4], fsm[4];
    const int t   = threadIdx.x;
    const int blk = blockIdx.x;

    // cooperative x prefetch: 320 float4, contiguous, all 256 lanes
    {
        const float4* xs = (const float4*)(x + blk * (RPB * LAT));
        sx[t] = xs[t];
        if (t < RPB * 10 - 256) sx[t + 256] = xs[t + 256];
    }

    // fold stage1 partials (kernel-boundary coherent) + stage wsum/bias.
    // split pair tables into scalar arrays: lane j reads bank j%32 ->
    // 2 lanes/bank (free, m136) vs float2's 4-way conflict (r14: 807K conflicts).
    if (t < 40) {
        float s = 0.f;
        #pragma unroll
        for (int j = 0; j < PBLK; ++j) s += ws[256 + j * 40 + t];
        sps[t] = s;
    } else if (t == 40) {
        float s = 0.f;
        #pragma unroll
        for (int j = 0; j < PBLK; ++j) s += ws[200 + j];
        spsq = s;
    }
    if (t >= 56 && t < 156) {
        const int j = t - 56;
        float2 v = ((const float2*)ws)[j];
        swx[j] = v.x; swy[j] = v.y;
    }
    if (t >= 156) {
        const int j = t - 156;
        float2 v = ((const float2*)bias)[j];
        sbx[j] = v.x; sby[j] = v.y;
    }
    __syncthreads();

    // phase 1: threads 0..31 (wave 0) compute d for this block's 32 rows
    float pmn = 0.f, psm = 0.f;
    if (t < RPB) {
        float ssq2 = 0.f, dot = 0.f;
        #pragma unroll
        for (int k = 0; k < 10; ++k) {
            float4 v = sx[t * 10 + k];
            ssq2 += v.x * v.x + v.y * v.y + v.z * v.z + v.w * v.w;
            dot  += v.x * sps[4 * k] + v.y * sps[4 * k + 1] +
                    v.z * sps[4 * k + 2] + v.w * sps[4 * k + 3];
        }
        const float d = sqrtf(2048.f * ssq2 - 2.f * dot + spsq);
        sd[t] = d;
        float mn = d, sm = d;
        #pragma unroll
        for (int off = 16; off > 0; off >>= 1) {   // 32 active lanes, same wave
            mn = fminf(mn, __shfl_down(mn, off, 64));
            sm += __shfl_down(sm, off, 64);
        }
        pmn = mn; psm = sm;
    }
    __syncthreads();

    // phase 2: write 32x200 output slab, 8B system-scope stores (r15-best)
    unsigned long long* o = (unsigned long long*)(out + 2);   // 8B-aligned
    const int base = blk * (RPB * 100);
    for (int idx = t; idx < RPB * 100; idx += 256) {
        const int i = idx / 100;             // row within block (magic-mul)
        const int j = idx - i * 100;         // column pair
        const float dd = sd[i];
        __hip_atomic_store(o + base + idx,
                           pack2f(dd * swx[j] + sbx[j], dd * swy[j] + sby[j]),
                           __ATOMIC_RELAXED, __HIP_MEMORY_SCOPE_SYSTEM);
    }

    // hierarchical arrival (r7-proven)
    unsigned long long* pptr = (unsigned long long*)ws + 1024;
    int* cnt1 = (int*)ws + 6400;
    int* cnt2 = (int*)ws + 8448;
    if (t == 0) {
        __hip_atomic_store(pptr + blk, pack2f(pmn, psm),
                           __ATOMIC_RELAXED, __HIP_MEMORY_SCOPE_AGENT);
        asm volatile("s_waitcnt vmcnt(0)" ::: "memory");  // partial is at LLC
        const int c = blk & (NB1 - 1);
        int last = 0;
        int p1 = __hip_atomic_fetch_add(cnt1 + c * 32, 1, __ATOMIC_RELAXED,
                                        __HIP_MEMORY_SCOPE_AGENT);
        if (p1 == FBLK / NB1 - 1) {
            int p2 = __hip_atomic_fetch_add(cnt2, 1, __ATOMIC_RELAXED,
                                            __HIP_MEMORY_SCOPE_AGENT);
            last = (p2 == NB1 - 1);
        }
        islast = last;
    }
    __syncthreads();

    // last-arriving block reduces all 1024 partials
    if (islast) {
        float mn = 3.4e38f, sm = 0.f;
        #pragma unroll
        for (int j = 0; j < FBLK / 256; ++j) {
            unsigned long long v = __hip_atomic_load(pptr + j * 256 + t,
                                                     __ATOMIC_RELAXED,
                                                     __HIP_MEMORY_SCOPE_AGENT);
            union { unsigned long long u; float f[2]; } c2; c2.u = v;
            mn = fminf(mn, c2.f[0]);
            sm += c2.f[1];
        }
        #pragma unroll
        for (int off = 32; off > 0; off >>= 1) {
            mn = fminf(mn, __shfl_down(mn, off, 64));
            sm += __shfl_down(sm, off, 64);
        }
        if ((t & 63) == 0) { fmn[t >> 6] = mn; fsm[t >> 6] = sm; }
        __syncthreads();
        if (t == 0) {
            out[0] = fminf(fminf(fmn[0], fmn[1]), fminf(fmn[2], fmn[3]));
            out[1] = (fsm[0] + fsm[1] + fsm[2] + fsm[3]) * (1.0f / 32768.0f);
        }
    }
}

extern "C" void kernel_launch(void* const* d_in, const int* in_sizes, int n_in,
                              void* d_out, int out_size, void* d_ws, size_t ws_size,
                              hipStream_t stream) {
    const float* x      = (const float*)d_in[0];
    const float* protos = (const float*)d_in[1];
    const float* w      = (const float*)d_in[2];
    const float* bias   = (const float*)d_in[3];
    float* out = (float*)d_out;
    float* ws  = (float*)d_ws;

    pc_stage1<<<NOUT + PBLK, 320, 0, stream>>>(protos, w, ws);
    pc_distout<<<FBLK, 256, 0, stream>>>(x, bias, ws, out);
}